// Round 6
// baseline (283.079 us; speedup 1.0000x reference)
//
#include <hip/hip_runtime.h>
#include <hip/hip_fp16.h>

#define WIDTH   640
#define HEIGHT  384
#define PLANE   (WIDTH*HEIGHT)
#define STRIP_H 48
#define NSTRIP  8                 /* 384/48 */
#define NBLK    (96*NSTRIP)       /* 768 = 3 blocks/CU exactly */
#define CS_M    716               /* mapped width: m(s)=s+s/10, m(649)=713 */
#define INV_N   (1.0f/23592960.0f)
#define C1S     1.4641f           /* 0.01^2 * 121^2 */
#define C2S     13.17690f         /* 0.03^2 * 121^2 */

__device__ __forceinline__ __half2 packh2(float a, float b) {
    __fp16 __attribute__((ext_vector_type(2))) v = __builtin_amdgcn_cvt_pkrtz(a, b);
    __half2 r; __builtin_memcpy(&r, &v, sizeof(r)); return r;
}

__global__ __launch_bounds__(256, 3)
void ssim_main(const float* __restrict__ pred, const float* __restrict__ targ,
               float* __restrict__ ws)
{
    // column sums (Sp, St, Spp+Stt, Spt), swizzled index m(s)=s+s/10, s=x+5.
    // Phase-B lane stride becomes 11 float4s -> 11L mod 8 covers all bank-quads
    // evenly (gcd(11,8)=1): structurally minimal b128 banking, zero conflicts.
    __shared__ float4 cs[4][CS_M];     // 45.8 KB -> 3 blocks/CU
    __shared__ float  red[4];

    const int tid   = threadIdx.x;
    const int plane = blockIdx.x % 96;
    const int strip = blockIdx.x / 96;
    const int y0s   = strip * STRIP_H;
    const float* __restrict__ P = pred + plane * PLANE;
    const float* __restrict__ T = targ + plane * PLANE;

    // zero horizontal-halo slots (s in [0,5) and [645,650)) for all 4 rows
    if (tid < 40) {
        int k = tid / 10, j = tid % 10;
        int s = (j < 5) ? j : (640 + j);
        cs[k][s + s / 10] = make_float4(0.f, 0.f, 0.f, 0.f);
    }

    // per-chunk swizzled write index (fixed per thread; hoisted out of the loop)
    int mA[3];
#pragma unroll
    for (int c = 0; c < 3; ++c) { int s = tid + (c << 8) + 5; mA[c] = s + s / 10; }

    // fp16 pixel ring in REGISTERS: 12 slots, advance 4/group -> static indices
    __half2 ring[3][12];
    float S[3][4];

#pragma unroll
    for (int c = 0; c < 3; ++c) {
        S[c][0] = S[c][1] = S[c][2] = S[c][3] = 0.f;
        ring[c][11] = packh2(0.f, 0.f);
        int x = tid + (c << 8);
        if (x < WIDTH) {
#pragma unroll
            for (int j = 0; j < 11; ++j) {
                int yy = y0s - 6 + j;
                __half2 h = (yy >= 0) ? packh2(P[yy*WIDTH + x], T[yy*WIDTH + x])
                                      : packh2(0.f, 0.f);
                ring[c][j] = h;
                float2 v = __half22float2(h);
                S[c][0] += v.x;  S[c][1] += v.y;
                S[c][2] += v.x*v.x + v.y*v.y;
                S[c][3] += v.x*v.y;
            }
        } else {
#pragma unroll
            for (int j = 0; j < 11; ++j) ring[c][j] = packh2(0.f, 0.f);
        }
    }

    float pfP[3][4], pfT[3][4];
    auto prefetch = [&](int G) {
        const int yb = y0s + (G << 2) + 5;
#pragma unroll
        for (int c = 0; c < 3; ++c) {
            int x = tid + (c << 8);
            if (x < WIDTH) {
#pragma unroll
                for (int k = 0; k < 4; ++k) {
                    int yn = yb + k;
                    bool v = (yn < HEIGHT);
                    pfP[c][k] = v ? P[yn*WIDTH + x] : 0.f;
                    pfT[c][k] = v ? T[yn*WIDTH + x] : 0.f;
                }
            }
        }
    };
    prefetch(0);

    float acc = 0.f;

    for (int o = 0; o < 4; ++o) {
#pragma unroll
        for (int u = 0; u < 3; ++u) {
            const int G = 3 * o + u;

            // ---- Phase A: advance 4 rows; ring old value from registers ----
#pragma unroll
            for (int c = 0; c < 3; ++c) {
                int x = tid + (c << 8);
                if (x < WIDTH) {
#pragma unroll
                    for (int k = 0; k < 4; ++k) {
                        const int sr = 4 * u + k;                 // read slot
                        const int sw = (4 * u + k + 11) % 12;     // write slot
                        __half2 hn = packh2(pfP[c][k], pfT[c][k]);
                        __half2 ho = ring[c][sr];
                        ring[c][sw] = hn;
                        float2 n  = __half22float2(hn);
                        float2 od = __half22float2(ho);
                        S[c][0] += n.x - od.x;
                        S[c][1] += n.y - od.y;
                        S[c][2] += n.x*n.x + n.y*n.y - od.x*od.x - od.y*od.y;
                        S[c][3] += n.x*n.y - od.x*od.y;
                        cs[k][mA[c]] = make_float4(S[c][0], S[c][1], S[c][2], S[c][3]);
                    }
                }
            }
            if (G + 1 < 12) prefetch(G + 1);   // loads overlap barrier + Phase B
            __syncthreads();

            // ---- Phase B: 4 waves x 1 row; 10 px/lane sliding window ----
            {
                const int k    = tid >> 6;
                const int lane = tid & 63;
                const float4* csk = &cs[k][11 * lane];

                float4 w[9];
                float4 B = make_float4(0.f, 0.f, 0.f, 0.f);
#pragma unroll
                for (int j = 0; j <= 10; ++j) {
                    float4 v = csk[(j <= 9) ? j : 11];   // m = 11L + j (+1 pad at j=10)
                    if (j < 9) w[j] = v;
                    B.x += v.x; B.y += v.y; B.z += v.z; B.w += v.w;
                }
#pragma unroll
                for (int i = 0; i < 10; ++i) {
                    if (i > 0) {
                        float4 n = csk[11 + i];          // window col 10L+10+i
                        B.x += n.x - w[i-1].x;
                        B.y += n.y - w[i-1].y;
                        B.z += n.z - w[i-1].z;
                        B.w += n.w - w[i-1].w;
                    }
                    // scaled-sum SSIM: all terms multiplied by 121^2 per factor
                    float uu = B.x, vv = B.y, wq = B.z, zz = B.w;
                    float uv = uu * vv;
                    float ss = uu * uu + vv * vv;
                    float n1 = fmaf(2.f, uv, C1S);
                    float t  = fmaf(242.f, zz, C2S);
                    float n2 = fmaf(-2.f, uv, t);
                    float d1 = ss + C1S;
                    float d2 = fmaf(121.f, wq, C2S) - ss;
                    acc += (n1 * n2) * __builtin_amdgcn_rcpf(d1 * d2);
                }
            }
            __syncthreads();
        }
    }

    // ---- block reduction -> one plain store per block ----
#pragma unroll
    for (int off = 32; off >= 1; off >>= 1)
        acc += __shfl_down(acc, off);
    if ((tid & 63) == 0) red[tid >> 6] = acc;
    __syncthreads();
    if (tid == 0)
        ws[blockIdx.x] = red[0] + red[1] + red[2] + red[3];
}

__global__ void ssim_reduce(const float* __restrict__ ws, float* __restrict__ out)
{
    __shared__ float red[4];
    const int tid = threadIdx.x;
    float s = ws[tid] + ws[tid + 256] + ws[tid + 512];
#pragma unroll
    for (int off = 32; off >= 1; off >>= 1)
        s += __shfl_down(s, off);
    if ((tid & 63) == 0) red[tid >> 6] = s;
    __syncthreads();
    if (tid == 0)
        out[0] = 1.0f - (red[0] + red[1] + red[2] + red[3]) * INV_N;
}

extern "C" void kernel_launch(void* const* d_in, const int* in_sizes, int n_in,
                              void* d_out, int out_size, void* d_ws, size_t ws_size,
                              hipStream_t stream) {
    const float* pred = (const float*)d_in[0];
    const float* targ = (const float*)d_in[1];
    float* out = (float*)d_out;
    float* ws  = (float*)d_ws;          // 768 floats of partial sums
    ssim_main<<<NBLK, 256, 0, stream>>>(pred, targ, ws);
    ssim_reduce<<<1, 256, 0, stream>>>(ws, out);
}

// Round 7
// 255.760 us; speedup vs baseline: 1.1068x; 1.1068x over previous
//
#include <hip/hip_runtime.h>

#define WIDTH   640
#define HEIGHT  384
#define PLANE   (WIDTH*HEIGHT)
#define STRIP_H 48
#define NSTRIP  8                 /* 384/48 */
#define NBLK    (96*NSTRIP)       /* 768 = 3 blocks/CU exactly */
#define CS_M    716               /* mapped width: m(s)=s+s/10, m(649)=713 */
#define GROUPS  12                /* STRIP_H/4 */
#define INV_N   (1.0f/23592960.0f)
#define C1S     1.4641f           /* 0.01^2 * 121^2 */
#define C2S     13.17690f         /* 0.03^2 * 121^2 */

__global__ __launch_bounds__(256, 3)
void ssim_main(const float* __restrict__ pred, const float* __restrict__ targ,
               float* __restrict__ ws)
{
    // column sums (Sp, St, Spp+Stt, Spt), swizzled index m(s)=s+s/10, s=x+5.
    // Phase-B lane stride = 11 float4s: measured conflict-free in R6
    // (SQ_LDS_BANK_CONFLICT 24.2M -> 2.4M). 45.8 KB -> 3 blocks/CU.
    __shared__ float4 cs[4][CS_M];
    __shared__ float  red[4];

    const int tid   = threadIdx.x;
    const int plane = blockIdx.x % 96;   // vertical neighbors differ by 96 -> same XCD
    const int strip = blockIdx.x / 96;   // 0..7
    const int y0s   = strip * STRIP_H;
    const float* __restrict__ P = pred + plane * PLANE;
    const float* __restrict__ T = targ + plane * PLANE;

    // zero horizontal-halo slots (s in [0,5) and [645,650)) for all 4 rows
    if (tid < 40) {
        int k = tid / 10, j = tid % 10;
        int s = (j < 5) ? j : (640 + j);
        cs[k][s + s / 10] = make_float4(0.f, 0.f, 0.f, 0.f);
    }

    // per-chunk swizzled write index (fixed per thread)
    int mA[3];
#pragma unroll
    for (int c = 0; c < 3; ++c) { int s = tid + (c << 8) + 5; mA[c] = s + s / 10; }

    // ---- Bootstrap: column sums over rows [y0s-6, y0s+4], pure fp32.
    //      Old-row subtraction later re-reads the SAME fp32 values -> exact.
    float S[3][4];
#pragma unroll
    for (int c = 0; c < 3; ++c) {
        S[c][0] = S[c][1] = S[c][2] = S[c][3] = 0.f;
        int x = tid + (c << 8);
        if (x < WIDTH) {
            for (int yy = y0s - 6; yy <= y0s + 4; ++yy) {
                if (yy >= 0) {
                    float pv = P[yy*WIDTH + x];
                    float tv = T[yy*WIDTH + x];
                    S[c][0] += pv;  S[c][1] += tv;
                    S[c][2] += pv*pv + tv*tv;
                    S[c][3] += pv*tv;
                }
            }
        }
    }

    // register prefetch for the 4 NEW rows entering the window each group
    float nP[3][4], nT[3][4];
    auto prefetch = [&](int G) {
        const int yb = y0s + (G << 2) + 5;
#pragma unroll
        for (int c = 0; c < 3; ++c) {
            int x = tid + (c << 8);
            if (x < WIDTH) {
#pragma unroll
                for (int k = 0; k < 4; ++k) {
                    int yn = yb + k;
                    bool v = (yn < HEIGHT);
                    nP[c][k] = v ? P[yn*WIDTH + x] : 0.f;
                    nT[c][k] = v ? T[yn*WIDTH + x] : 0.f;
                }
            }
        }
    };
    prefetch(0);

    float acc = 0.f;

    for (int g = 0; g < GROUPS; ++g) {
        const int y0 = y0s + (g << 2);

        // consume prefetch, immediately issue next group's loads
        float cPn[3][4], cTn[3][4];
#pragma unroll
        for (int c = 0; c < 3; ++c)
#pragma unroll
            for (int k = 0; k < 4; ++k) { cPn[c][k] = nP[c][k]; cTn[c][k] = nT[c][k]; }
        if (g + 1 < GROUPS) prefetch(g + 1);

        // ---- Phase A: advance 4 rows; OLD rows re-read from global (L2/L3
        //      resident: 43 MB total lag-window across the chip << 256 MB L3)
#pragma unroll
        for (int c = 0; c < 3; ++c) {
            int x = tid + (c << 8);
            if (x < WIDTH) {
#pragma unroll
                for (int k = 0; k < 4; ++k) {
                    int yo = y0 + k - 6;
                    float oP = (yo >= 0) ? P[yo*WIDTH + x] : 0.f;
                    float oT = (yo >= 0) ? T[yo*WIDTH + x] : 0.f;
                    float pn = cPn[c][k], tn = cTn[c][k];
                    S[c][0] += pn - oP;
                    S[c][1] += tn - oT;
                    S[c][2] += pn*pn + tn*tn - oP*oP - oT*oT;
                    S[c][3] += pn*tn - oP*oT;
                    cs[k][mA[c]] = make_float4(S[c][0], S[c][1], S[c][2], S[c][3]);
                }
            }
        }
        __syncthreads();

        // ---- Phase B: 4 waves x 1 row; 10 px/lane sliding window (R6 verbatim:
        //      measured conflict-free) ----
        {
            const int k    = tid >> 6;
            const int lane = tid & 63;
            const float4* csk = &cs[k][11 * lane];

            float4 w[9];
            float4 B = make_float4(0.f, 0.f, 0.f, 0.f);
#pragma unroll
            for (int j = 0; j <= 10; ++j) {
                float4 v = csk[(j <= 9) ? j : 11];   // m = 11L + j (+1 pad at j=10)
                if (j < 9) w[j] = v;
                B.x += v.x; B.y += v.y; B.z += v.z; B.w += v.w;
            }
#pragma unroll
            for (int i = 0; i < 10; ++i) {
                if (i > 0) {
                    float4 n = csk[11 + i];          // window col 10L+10+i
                    B.x += n.x - w[i-1].x;
                    B.y += n.y - w[i-1].y;
                    B.z += n.z - w[i-1].z;
                    B.w += n.w - w[i-1].w;
                }
                // scaled-sum SSIM: constants scaled by 121^2 per factor
                float uu = B.x, vv = B.y, wq = B.z, zz = B.w;
                float uv = uu * vv;
                float ss = uu * uu + vv * vv;
                float n1 = fmaf(2.f, uv, C1S);
                float t  = fmaf(242.f, zz, C2S);
                float n2 = fmaf(-2.f, uv, t);
                float d1 = ss + C1S;
                float d2 = fmaf(121.f, wq, C2S) - ss;
                acc += (n1 * n2) * __builtin_amdgcn_rcpf(d1 * d2);
            }
        }
        __syncthreads();
    }

    // ---- block reduction -> one plain store per block ----
#pragma unroll
    for (int off = 32; off >= 1; off >>= 1)
        acc += __shfl_down(acc, off);
    if ((tid & 63) == 0) red[tid >> 6] = acc;
    __syncthreads();
    if (tid == 0)
        ws[blockIdx.x] = red[0] + red[1] + red[2] + red[3];
}

__global__ void ssim_reduce(const float* __restrict__ ws, float* __restrict__ out)
{
    __shared__ float red[4];
    const int tid = threadIdx.x;
    float s = ws[tid] + ws[tid + 256] + ws[tid + 512];
#pragma unroll
    for (int off = 32; off >= 1; off >>= 1)
        s += __shfl_down(s, off);
    if ((tid & 63) == 0) red[tid >> 6] = s;
    __syncthreads();
    if (tid == 0)
        out[0] = 1.0f - (red[0] + red[1] + red[2] + red[3]) * INV_N;
}

extern "C" void kernel_launch(void* const* d_in, const int* in_sizes, int n_in,
                              void* d_out, int out_size, void* d_ws, size_t ws_size,
                              hipStream_t stream) {
    const float* pred = (const float*)d_in[0];
    const float* targ = (const float*)d_in[1];
    float* out = (float*)d_out;
    float* ws  = (float*)d_ws;          // 768 floats of partial sums
    ssim_main<<<NBLK, 256, 0, stream>>>(pred, targ, ws);
    ssim_reduce<<<1, 256, 0, stream>>>(ws, out);
}